// Round 3
// baseline (1253.756 us; speedup 1.0000x reference)
//
#include <hip/hip_runtime.h>
#include <hip/hip_bf16.h>
#include <math.h>

#define NN 32000        // total nodes
#define EE 640000       // edges
#define CC 128          // hidden
#define HC 384          // H*C
#define FIN 1038
#define KP 1056         // FIN padded to multiple of 32
#define KT 33           // KP/32
#define BB 16           // graphs
#define NPG 2000
#define KK 400

// per-branch strides (float elements)
#define XLR_STR 12288000u
#define HBN_STR 4096000u
#define OFF_STR 32064u

// ---------------- workspace layout (float elements), 2 branches resident ----------------
// XL region holds fp16 xl (2 branches * 12288000 halves in half the region)
#define XL_OFF     0u            // 2 * 12288000
#define XR_OFF     24576000u     // 2 * 12288000
#define HBN_OFF    49152000u     // 2 * 4096000
#define SSRC_OFF   57344000u     // (free)
#define SEA_OFF    58624000u     // packed edges: 2 * 640000 int2 (8B) = exactly this region
#define CNT_OFF    61184000u     // zero block: cnt(2*32000)+bnsum(2*128)+bnsq(2*128)+meanea(4)
#define BNSUM_OFF  61248000u
#define BNSQ_OFF   61248256u
#define MEANEA_OFF 61248512u
#define ZERO_BYTES ((61248516u - 61184000u) * 4u)
#define OFFS_OFF   61248576u     // 2 * 32064
#define CUR_OFF    61312704u     // 2 * 32000
#define R_OFF      61376704u     // 2 * 32000
#define REL_OFF    61440704u     // 2 * 32000
#define SCORE_OFF  61504704u     // 2 * 32000
#define XB_OFF     61568704u     // 4096
#define WTH_OFF    61572800u     // 405504 (f16 weights use only 202752 fl worth)

typedef __attribute__((ext_vector_type(8))) _Float16 f16x8;
typedef __attribute__((ext_vector_type(2))) _Float16 f16x2;
typedef __attribute__((ext_vector_type(4))) float f32x4;
typedef __attribute__((ext_vector_type(8))) unsigned short us8;

typedef const __attribute__((address_space(1))) unsigned int* gp1_t;
typedef __attribute__((address_space(3))) unsigned int* lp3_t;
__device__ __forceinline__ void gl_lds16(const void* g, void* l) {
    __builtin_amdgcn_global_load_lds((gp1_t)g, (lp3_t)l, 16, 0, 0);
}

// ---------------- fused: dst histogram + edge-attr mean (both branches) ----------------
__global__ __launch_bounds__(256) void k_prep(const int* __restrict__ ei0, const int* __restrict__ ei1,
                                              const float* __restrict__ ea0, const float* __restrict__ ea1,
                                              int* __restrict__ cnt, float* __restrict__ meanea) {
    int b = blockIdx.x;
    int br = (b >= 2500);
    int tid = threadIdx.x;
    int e = (b - br * 2500) * 256 + tid;
    const int* ei = br ? ei1 : ei0;
    const float* ea = br ? ea1 : ea0;
    cnt += br * NN; meanea += br * 2;
    float s0 = 0.f, s1 = 0.f;
    if (e < EE) {
        atomicAdd(&cnt[ei[EE + e]], 1);
        float2 t = ((const float2*)ea)[e];
        s0 = t.x; s1 = t.y;
    }
    __shared__ float r0[256], r1[256];
    r0[tid] = s0; r1[tid] = s1; __syncthreads();
    for (int st = 128; st; st >>= 1) {
        if (tid < st) { r0[tid] += r0[tid + st]; r1[tid] += r1[tid + st]; }
        __syncthreads();
    }
    if (tid == 0) { atomicAdd(&meanea[0], r0[0]); atomicAdd(&meanea[1], r1[0]); }
}

// ---------------- exclusive scan over 32000 counters (1 block per branch) ----------------
__global__ __launch_bounds__(1024) void k_scan(const int* __restrict__ cnt, int* __restrict__ offs, int* __restrict__ cur) {
    int br = blockIdx.x;
    cnt += br * NN; offs += br * OFF_STR; cur += br * NN;
    __shared__ int sb[1024];
    int tid = threadIdx.x;
    int base = tid * 32;
    int s = 0;
    for (int i = 0; i < 32; i++) { int idx = base + i; s += (idx < NN) ? cnt[idx] : 0; }
    sb[tid] = s; __syncthreads();
    for (int off = 1; off < 1024; off <<= 1) {
        int v = (tid >= off) ? sb[tid - off] : 0;
        __syncthreads();
        sb[tid] += v;
        __syncthreads();
    }
    int run = sb[tid] - s;  // exclusive prefix
    for (int i = 0; i < 32; i++) {
        int idx = base + i;
        if (idx < NN) { int c = cnt[idx]; offs[idx] = run; cur[idx] = run; run += c; }
    }
    if (tid == 1023) offs[NN] = run;
}

// ---------------- scatter edges sorted by dst, packed {src, half2 ea} 8B (both branches) ----------------
__global__ __launch_bounds__(256) void k_scatter(const int* __restrict__ ei0, const int* __restrict__ ei1,
                                                 const float* __restrict__ ea0, const float* __restrict__ ea1,
                                                 int* __restrict__ cur, int2* __restrict__ sed) {
    int b = blockIdx.x;
    int br = (b >= 2500);
    int e = (b - br * 2500) * 256 + threadIdx.x;
    const int* ei = br ? ei1 : ei0;
    const float* ea = br ? ea1 : ea0;
    cur += br * NN; sed += br * EE;
    if (e < EE) {
        int d = ei[EE + e];
        int p = atomicAdd(&cur[d], 1);
        float2 t = ((const float2*)ea)[e];
        f16x2 h; h[0] = (_Float16)t.x; h[1] = (_Float16)t.y;
        int2 pk;
        pk.x = ei[e];
        pk.y = __builtin_bit_cast(int, h);
        sed[p] = pk;
    }
}

// ---------------- weights: transpose to N-major [768][1056], fp16 (single array) ----------------
__global__ __launch_bounds__(256) void k_cvtW(const float* __restrict__ Wl_, const float* __restrict__ Wr_,
                                              unsigned short* __restrict__ Bh) {
    int idx = blockIdx.x * 256 + threadIdx.x;
    if (idx >= 768 * (KP / 8)) return;
    int n = idx / (KP / 8);
    int seg = idx - n * (KP / 8);
    int c0 = seg * 8;
    const float* W = (n < HC) ? Wl_ : Wr_;
    int nc = (n < HC) ? n : n - HC;
    us8 h8;
#pragma unroll
    for (int j = 0; j < 8; ++j) {
        int k = c0 + j;
        float v = (k < FIN) ? W[(size_t)k * HC + nc] : 0.f;
        _Float16 h = (_Float16)v;   // RTN
        h8[j] = __builtin_bit_cast(unsigned short, h);
    }
    *(us8*)&Bh[(size_t)n * KP + c0] = h8;
}

// ---------------- MFMA GEMM, fp16, 2-phase software pipeline ----------------
// Per iter: issue B-DMA(t+1) + A-global-loads(t+1)->regs, MFMA(t), cvt+ds_write A(t+1),
// ONE barrier. B-DMA and A-loads stay in flight across the MFMA phase (T3-min + T14).
__global__ __launch_bounds__(256) void k_gemm2f(const float* __restrict__ x0, const float* __restrict__ x1,
                                                const unsigned short* __restrict__ Bh,
                                                const float* __restrict__ bias, float* __restrict__ ws) {
    __shared__ _Float16 sA[2][128 * 32], sB[2][128 * 32];
    const int bid = blockIdx.x;
    const int br = (bid >= 1504);
    const int b2 = br ? (bid - 1504) : bid;
    const float* x = br ? x1 : x0;
    _Float16* xlh = (_Float16*)(ws + XL_OFF) + (size_t)br * XLR_STR;
    float* xr = ws + XR_OFF + br * XLR_STR;

    const int xcd = b2 & 7, slot = b2 >> 3;
    const int t = xcd * 188 + slot;          // 1504/8 = 188 slots per XCD
    if (t >= 1500) return;
    const int mt = t / 6, nt = t - mt * 6;
    const int bm = mt * 128, bn = nt * 128;

    const int tid = threadIdx.x;
    const int wave = tid >> 6, lane = tid & 63;
    const int wm = (wave >> 1) * 64, wn = (wave & 1) * 64;
    const int quad = lane >> 4, l15 = lane & 15;

    // B staging (global_load_lds, f16)
    const int srow = wave * 16 + (lane >> 2);
    const int scol = (lane & 3) * 8;
    const size_t gB0 = (size_t)(bn + srow) * KP + scol;
    const size_t gB1 = (size_t)(bn + 64 + srow) * KP + scol;
    const int lB0 = (wave * 16) * 32 + lane * 8;
    const int lB1 = (64 + wave * 16) * 32 + lane * 8;

    // A staging: wave w covers rows w*32..w*32+31; 8 fp32/lane/rep, 2 reps
    const int arow0 = wave * 32 + (lane >> 2);   // + rep*16
    const int acol = (lane & 3) * 8;

    float af[2][8];   // A prefetch registers

#define LOADA(KT_) do {                                                         \
        int gcol = (KT_) * 32 + acol;                                           \
        if (gcol >= FIN) gcol = 0;                                              \
        _Pragma("unroll")                                                       \
        for (int rep = 0; rep < 2; ++rep) {                                     \
            const float* gp = x + (size_t)(bm + arow0 + rep * 16) * FIN + gcol; \
            float2 v01 = ((const float2*)gp)[0];                                \
            float2 v23 = ((const float2*)gp)[1];                                \
            float2 v45 = ((const float2*)gp)[2];                                \
            float2 v67 = ((const float2*)gp)[3];                                \
            af[rep][0] = v01.x; af[rep][1] = v01.y;                             \
            af[rep][2] = v23.x; af[rep][3] = v23.y;                             \
            af[rep][4] = v45.x; af[rep][5] = v45.y;                             \
            af[rep][6] = v67.x; af[rep][7] = v67.y;                             \
        } } while (0)

#define CVTWRITE(BUF_) do {                                                     \
        _Pragma("unroll")                                                       \
        for (int rep = 0; rep < 2; ++rep) {                                     \
            f16x8 a;                                                            \
            _Pragma("unroll")                                                   \
            for (int j = 0; j < 8; ++j) a[j] = (_Float16)af[rep][j];            \
            *(f16x8*)&sA[BUF_][(arow0 + rep * 16) * 32 + acol] = a;             \
        } } while (0)

    f32x4 acc[4][4];
#pragma unroll
    for (int i = 0; i < 4; ++i)
#pragma unroll
        for (int j = 0; j < 4; ++j) {
            f32x4 z = {0.f, 0.f, 0.f, 0.f};
            acc[i][j] = z;
        }

    const int aoff0 = (wm + l15) * 32 + quad * 8;   // + i*512 (f16 elements)
    const int boff0 = (wn + l15) * 32 + quad * 8;   // + j*512

    // prologue: stage kt=0 into buf 0
    gl_lds16(Bh + gB0, &sB[0][lB0]);
    gl_lds16(Bh + gB1, &sB[0][lB1]);
    LOADA(0);
    CVTWRITE(0);
    __syncthreads();

    for (int kt = 0; kt < KT; ++kt) {
        const int cur = kt & 1, nxt = cur ^ 1;
        const bool pf = (kt + 1 < KT);
        if (pf) {
            const int kc = (kt + 1) * 32;
            gl_lds16(Bh + gB0 + kc, &sB[nxt][lB0]);
            gl_lds16(Bh + gB1 + kc, &sB[nxt][lB1]);
            LOADA(kt + 1);
        }
        f16x8 bfr[4];
#pragma unroll
        for (int j = 0; j < 4; ++j) bfr[j] = *(const f16x8*)&sB[cur][boff0 + j * 512];
#pragma unroll
        for (int i = 0; i < 4; ++i) {
            f16x8 a = *(const f16x8*)&sA[cur][aoff0 + i * 512];
#pragma unroll
            for (int j = 0; j < 4; ++j)
                acc[i][j] = __builtin_amdgcn_mfma_f32_16x16x32_f16(a, bfr[j], acc[i][j], 0, 0, 0);
        }
        if (pf) CVTWRITE(nxt);
        __syncthreads();   // drains vmcnt (B DMA + A loads) + lgkm (A ds_write); protects cur for next overwrite
    }
#undef LOADA
#undef CVTWRITE

    // epilogue: C/D layout col=lane&15, row=quad*4+reg.
    const bool isL = (nt < 3);
    if (isL) {
#pragma unroll
        for (int j = 0; j < 4; ++j) {
            const int ncol = wn + j * 16 + l15;
            const float bj = bias[bn + ncol];
#pragma unroll
            for (int i = 0; i < 4; ++i) {
#pragma unroll
                for (int r = 0; r < 4; ++r) {
                    int m = bm + wm + i * 16 + quad * 4 + r;
                    xlh[(size_t)m * HC + bn + ncol] = (_Float16)(acc[i][j][r] + bj);
                }
            }
        }
    } else {
        const int nbase = bn - HC;
#pragma unroll
        for (int j = 0; j < 4; ++j) {
            const int ncol = wn + j * 16 + l15;
#pragma unroll
            for (int i = 0; i < 4; ++i) {
#pragma unroll
                for (int r = 0; r < 4; ++r) {
                    int m = bm + wm + i * 16 + quad * 4 + r;
                    xr[(size_t)m * HC + nbase + ncol] = acc[i][j][r];
                }
            }
        }
    }
}

// ---------------- fused GATv2 aggregation: one wave per node, 2 edges/iter (32-lane halves) ----------------
__global__ __launch_bounds__(256) void k_gat(const unsigned short* __restrict__ xlhb, const float* __restrict__ xrb,
                                             const int* __restrict__ offsb, const int2* __restrict__ sedb,
                                             const float* __restrict__ meaneab,
                                             const float* __restrict__ We, const float* __restrict__ att,
                                             const float* __restrict__ conv_bias, float* __restrict__ houtb) {
    int gwave = (blockIdx.x * 256 + threadIdx.x) >> 6;
    int lane = threadIdx.x & 63;
    int half = lane >> 5, l32 = lane & 31;
    int br = (gwave >= NN);
    int node = gwave - br * NN;
    const _Float16* xlh = (const _Float16*)xlhb + (size_t)br * XLR_STR;
    const float* xr = xrb + br * XLR_STR;
    const int* offs = offsb + br * OFF_STR;
    const int2* sed = sedb + br * EE;
    const float* meanea = meaneab + br * 2;
    float* hout = houtb + br * HBN_STR;

    // per-lane constants: pair q = l32 + 32*jj holds channels (2q, 2q+1); head = jj>>1
    f16x2 we0p[6], we1p[6], attp[6], xrp[6];
    const float2* xrw = (const float2*)(xr + (size_t)node * HC);
#pragma unroll
    for (int jj = 0; jj < 6; ++jj) {
        int q = l32 + 32 * jj;
        float2 w0 = ((const float2*)We)[q];
        float2 w1 = ((const float2*)(We + HC))[q];
        float2 av = ((const float2*)att)[q];
        float2 xv = xrw[q];
        we0p[jj][0] = (_Float16)w0.x; we0p[jj][1] = (_Float16)w0.y;
        we1p[jj][0] = (_Float16)w1.x; we1p[jj][1] = (_Float16)w1.y;
        attp[jj][0] = (_Float16)av.x; attp[jj][1] = (_Float16)av.y;
        xrp[jj][0]  = (_Float16)xv.x; xrp[jj][1]  = (_Float16)xv.y;
    }
    _Float16 meh0 = (_Float16)(meanea[0] * (1.0f / EE));
    _Float16 meh1 = (_Float16)(meanea[1] * (1.0f / EE));

    int p0 = offs[node], p1 = offs[node + 1];
    int cntE = p1 - p0;
    int iters = (cntE + 2) >> 1;   // virtual list: t=0 self-loop, t=1..cntE real edges

    float den0 = 0.f, den1 = 0.f, den2 = 0.f;
    float accv[12];
#pragma unroll
    for (int k = 0; k < 12; ++k) accv[k] = 0.f;

    const f16x2 zero2 = {(_Float16)0.f, (_Float16)0.f};
    const f16x2 c02 = {(_Float16)0.2f, (_Float16)0.2f};

    for (int i = 0; i < iters; ++i) {
        int t = 2 * i + half;
        bool self = (t == 0);
        bool valid = (t <= cntE);
        int p = p0 + t - 1;
        if (p < p0) p = p0;
        if (p > EE - 1) p = EE - 1;
        int2 pk = sed[p];
        f16x2 eh = __builtin_bit_cast(f16x2, pk.y);
        int s = self ? node : pk.x;
        _Float16 e0 = self ? meh0 : eh[0];
        _Float16 e1 = self ? meh1 : eh[1];
        f16x2 e0p, e1p;
        e0p[0] = e0; e0p[1] = e0;
        e1p[0] = e1; e1p[1] = e1;

        const f16x2* xrow = (const f16x2*)(xlh + (size_t)s * HC);
        f16x2 xv[6];
#pragma unroll
        for (int jj = 0; jj < 6; ++jj) xv[jj] = xrow[l32 + 32 * jj];

        float pr0 = 0.f, pr1 = 0.f, pr2 = 0.f;
#pragma unroll
        for (int jj = 0; jj < 6; ++jj) {
            f16x2 u = xrp[jj] + e0p * we0p[jj];
            u = u + e1p * we1p[jj];
            f16x2 m = xv[jj] + u;
            f16x2 mx = __builtin_elementwise_max(m, zero2);
            f16x2 mn = __builtin_elementwise_min(m, zero2);
            f16x2 lk = mx + mn * c02;
#if __has_builtin(__builtin_amdgcn_fdot2)
            if (jj < 2)      pr0 = __builtin_amdgcn_fdot2(lk, attp[jj], pr0, false);
            else if (jj < 4) pr1 = __builtin_amdgcn_fdot2(lk, attp[jj], pr1, false);
            else             pr2 = __builtin_amdgcn_fdot2(lk, attp[jj], pr2, false);
#else
            float c = (float)lk[0] * (float)attp[jj][0] + (float)lk[1] * (float)attp[jj][1];
            if (jj < 2) pr0 += c; else if (jj < 4) pr1 += c; else pr2 += c;
#endif
        }
        // butterfly within the 32-lane half
#pragma unroll
        for (int msk = 16; msk; msk >>= 1) {
            pr0 += __shfl_xor(pr0, msk);
            pr1 += __shfl_xor(pr1, msk);
            pr2 += __shfl_xor(pr2, msk);
        }
        float w0 = valid ? __expf(pr0) : 0.f;
        float w1 = valid ? __expf(pr1) : 0.f;
        float w2 = valid ? __expf(pr2) : 0.f;
        den0 += w0; den1 += w1; den2 += w2;
#pragma unroll
        for (int jj = 0; jj < 6; ++jj) {
            float wh = (jj < 2) ? w0 : ((jj < 4) ? w1 : w2);
            accv[2 * jj]     += wh * (float)xv[jj][0];
            accv[2 * jj + 1] += wh * (float)xv[jj][1];
        }
    }

    // merge halves
#pragma unroll
    for (int k = 0; k < 12; ++k) accv[k] += __shfl_xor(accv[k], 32);
    den0 += __shfl_xor(den0, 32);
    den1 += __shfl_xor(den1, 32);
    den2 += __shfl_xor(den2, 32);

    if (half == 0) {
        float i0 = 1.f / den0, i1 = 1.f / den1, i2 = 1.f / den2;
#pragma unroll
        for (int jja = 0; jja < 2; ++jja) {
#pragma unroll
            for (int b = 0; b < 2; ++b) {
                int c = (((jja * 32 + l32) << 1) | b);
                float o = (accv[2 * jja + b] * i0 + accv[2 * (jja + 2) + b] * i1 +
                           accv[2 * (jja + 4) + b] * i2) * (1.f / 3.f) + conv_bias[c];
                o = (o > 0.f) ? o : 0.1f * o;
                hout[(size_t)node * CC + c] = o;
            }
        }
    }
}

// ---------------- batchnorm stats (both branches) ----------------
__global__ __launch_bounds__(256) void k_bnstats(const float* __restrict__ hb, float* __restrict__ bnsumb, float* __restrict__ bnsqb) {
    int b = blockIdx.x;
    int br = b >> 9, lb = b & 511;
    const float* h = hb + br * HBN_STR;
    float* bnsum = bnsumb + br * CC;
    float* bnsq = bnsqb + br * CC;
    int c = threadIdx.x & 127;
    int row0 = lb * 2 + (threadIdx.x >> 7);
    float s = 0.f, ss = 0.f;
    for (int n = row0; n < NN; n += 1024) {
        float v = h[(size_t)n * CC + c];
        s += v; ss += v * v;
    }
    atomicAdd(&bnsum[c], s);
    atomicAdd(&bnsq[c], ss);
}

// ---------------- BN apply (folds bnfinal) + scorer dot products (both branches) ----------------
__global__ __launch_bounds__(256) void k_bnapply(float* __restrict__ hb, const float* __restrict__ bnsumb,
                                                 const float* __restrict__ bnsqb,
                                                 const float* __restrict__ gamma, const float* __restrict__ beta,
                                                 const float* __restrict__ wroot,
                                                 const float* __restrict__ wrel, float* __restrict__ r_b, float* __restrict__ rel_b) {
    int gwave = (blockIdx.x * 256 + threadIdx.x) >> 6;
    int lane = threadIdx.x & 63;
    int br = (gwave >= NN);
    int wave = gwave - br * NN;
    float* h = hb + br * HBN_STR;
    const float* bnsum = bnsumb + br * CC;
    const float* bnsq = bnsqb + br * CC;
    float* r_ = r_b + br * NN;
    float* rel_ = rel_b + br * NN;

    float mu0 = bnsum[lane] * (1.f / NN);
    float var0 = bnsq[lane] * (1.f / NN) - mu0 * mu0;
    float sc0 = gamma[lane] * rsqrtf(var0 + 1e-5f);
    float sh0 = beta[lane] - mu0 * sc0;
    float mu1 = bnsum[64 + lane] * (1.f / NN);
    float var1 = bnsq[64 + lane] * (1.f / NN) - mu1 * mu1;
    float sc1 = gamma[64 + lane] * rsqrtf(var1 + 1e-5f);
    float sh1 = beta[64 + lane] - mu1 * sc1;

    size_t base = (size_t)wave * CC;
    float v0 = h[base + lane], v1 = h[base + 64 + lane];
    v0 = v0 * sc0 + sh0;
    v1 = v1 * sc1 + sh1;
    h[base + lane] = v0;
    h[base + 64 + lane] = v1;
    float pr = v0 * wroot[lane] + v1 * wroot[64 + lane];
    float pl = v0 * wrel[lane] + v1 * wrel[64 + lane];
#pragma unroll
    for (int m = 32; m; m >>= 1) {
        pr += __shfl_xor(pr, m);
        pl += __shfl_xor(pl, m);
    }
    if (lane == 0) { r_[wave] = pr; rel_[wave] = pl; }
}

// ---------------- scorer aggregation + tanh (both branches) ----------------
__global__ __launch_bounds__(256) void k_score(const float* __restrict__ r_b, const float* __restrict__ rel_b,
                                               const int* __restrict__ offsb, const int2* __restrict__ sedb,
                                               const float* __restrict__ gcb, float* __restrict__ scoreb) {
    int gwave = (blockIdx.x * 256 + threadIdx.x) >> 6;
    int lane = threadIdx.x & 63;
    int br = (gwave >= NN);
    int wave = gwave - br * NN;
    const float* r_ = r_b + br * NN;
    const float* rel_ = rel_b + br * NN;
    const int* offs = offsb + br * OFF_STR;
    const int2* sed = sedb + br * EE;
    float* score = scoreb + br * NN;
    int p0 = offs[wave], p1 = offs[wave + 1];
    float s = 0.f;
    for (int p = p0 + lane; p < p1; p += 64) s += rel_[sed[p].x];
#pragma unroll
    for (int m = 32; m; m >>= 1) s += __shfl_xor(s, m);
    if (lane == 0) score[wave] = tanhf(r_[wave] + s + gcb[0]);
}

// ---------------- per-graph top-K (exact bitonic sort of 2048) + weighted mean pool ----------------
__global__ __launch_bounds__(1024) void k_topk(const float* __restrict__ scoreb, const float* __restrict__ hb,
                                               float* __restrict__ xbout) {
    __shared__ float sv[2048];
    __shared__ int si[2048];
    __shared__ float red[8][128];
    int b = blockIdx.x, tid = threadIdx.x;
    int br = b >> 4, g = b & 15;
    const float* score = scoreb + br * NN;
    const float* h = hb + br * HBN_STR;
    for (int i = tid; i < 2048; i += 1024) {
        sv[i] = (i < NPG) ? score[g * NPG + i] : -2.0f;  // scores in [-1,1]
        si[i] = i;
    }
    __syncthreads();
    for (int k = 2; k <= 2048; k <<= 1) {
        for (int j = k >> 1; j > 0; j >>= 1) {
            for (int t = tid; t < 2048; t += 1024) {
                int ixj = t ^ j;
                if (ixj > t) {
                    bool up = ((t & k) == 0);  // descending overall
                    float a = sv[t], bv = sv[ixj];
                    bool sw = up ? (a < bv) : (a > bv);
                    if (sw) {
                        sv[t] = bv; sv[ixj] = a;
                        int tmp = si[t]; si[t] = si[ixj]; si[ixj] = tmp;
                    }
                }
            }
            __syncthreads();
        }
    }
    int grp = tid >> 7, c = tid & 127;
    float a = 0.f;
    for (int kk = grp; kk < KK; kk += 8) {
        int node = g * NPG + si[kk];
        a += sv[kk] * h[(size_t)node * CC + c];
    }
    red[grp][c] = a;
    __syncthreads();
    if (tid < 128) {
        float v = (red[0][tid] + red[1][tid] + red[2][tid] + red[3][tid] +
                   red[4][tid] + red[5][tid] + red[6][tid] + red[7][tid]) * (1.f / KK);
        xbout[(br * BB + g) * CC + tid] = v;
    }
}

// ---------------- final MLP ----------------
__global__ __launch_bounds__(128) void k_mlp(const float* __restrict__ xb, const float* __restrict__ W1,
                                             const float* __restrict__ b1, const float* __restrict__ W2,
                                             const float* __restrict__ b2, const float* __restrict__ Wo,
                                             const float* __restrict__ bo, float* __restrict__ out) {
    int g = blockIdx.x, tid = threadIdx.x;
    __shared__ float xc[256], l1[128], l2[64];
    xc[tid] = xb[g * CC + tid];
    xc[128 + tid] = xb[BB * CC + g * CC + tid];
    __syncthreads();
    float s = b1[tid];
    for (int i = 0; i < 256; i++) s += xc[i] * W1[i * 128 + tid];
    l1[tid] = (s > 0.f) ? s : 0.1f * s;
    __syncthreads();
    if (tid < 64) {
        float s2 = b2[tid];
        for (int i = 0; i < 128; i++) s2 += l1[i] * W2[i * 64 + tid];
        l2[tid] = (s2 > 0.f) ? s2 : 0.1f * s2;
    }
    __syncthreads();
    if (tid < 64) {
        float p = l2[tid] * Wo[tid];
#pragma unroll
        for (int m = 32; m; m >>= 1) p += __shfl_xor(p, m);
        if (tid == 0) out[g] = 1.f / (1.f + __expf(-(p + bo[0])));
    }
}

extern "C" void kernel_launch(void* const* d_in, const int* in_sizes, int n_in,
                              void* d_out, int out_size, void* d_ws, size_t ws_size,
                              hipStream_t stream) {
    (void)in_sizes; (void)n_in; (void)out_size; (void)ws_size;
    const float* x0   = (const float*)d_in[0];
    const float* x1   = (const float*)d_in[1];
    const int*   ei0  = (const int*)d_in[2];
    const int*   ei1  = (const int*)d_in[3];
    const float* ea0  = (const float*)d_in[4];
    const float* ea1  = (const float*)d_in[5];
    const float* Wl   = (const float*)d_in[6];
    const float* bl   = (const float*)d_in[7];
    const float* Wr   = (const float*)d_in[8];
    const float* We   = (const float*)d_in[9];
    const float* att  = (const float*)d_in[10];
    const float* cb   = (const float*)d_in[11];
    const float* gam  = (const float*)d_in[12];
    const float* bet  = (const float*)d_in[13];
    const float* wrel = (const float*)d_in[14];
    const float* wroot= (const float*)d_in[15];
    const float* gcb  = (const float*)d_in[16];
    const float* W1   = (const float*)d_in[17];
    const float* b1   = (const float*)d_in[18];
    const float* W2   = (const float*)d_in[19];
    const float* b2   = (const float*)d_in[20];
    const float* Wo   = (const float*)d_in[21];
    const float* bo   = (const float*)d_in[22];

    float* ws = (float*)d_ws;
    float*  hbn   = ws + HBN_OFF;
    int2*   sed   = (int2*)(ws + SEA_OFF);
    int*    cnt   = (int*)(ws + CNT_OFF);
    float*  bnsum = ws + BNSUM_OFF;
    float*  bnsq  = ws + BNSQ_OFF;
    float*  meanea= ws + MEANEA_OFF;
    int*    offs  = (int*)(ws + OFFS_OFF);
    int*    cur   = (int*)(ws + CUR_OFF);
    float*  r_    = ws + R_OFF;
    float*  rel_  = ws + REL_OFF;
    float*  score = ws + SCORE_OFF;
    float*  xb    = ws + XB_OFF;
    unsigned short* Wth = (unsigned short*)(ws + WTH_OFF);
    unsigned short* xlh = (unsigned short*)(ws + XL_OFF);
    float*  xr    = ws + XR_OFF;

    hipMemsetAsync(cnt, 0, ZERO_BYTES, stream);  // cnt + bnsum + bnsq + meanea, both branches
    k_cvtW<<<(768 * (KP / 8) + 255) / 256, 256, 0, stream>>>(Wl, Wr, Wth);

    k_prep<<<5000, 256, 0, stream>>>(ei0, ei1, ea0, ea1, cnt, meanea);
    k_scan<<<2, 1024, 0, stream>>>(cnt, offs, cur);
    k_scatter<<<5000, 256, 0, stream>>>(ei0, ei1, ea0, ea1, cur, sed);

    k_gemm2f<<<3008, 256, 0, stream>>>(x0, x1, Wth, bl, ws);

    k_gat<<<16000, 256, 0, stream>>>(xlh, xr, offs, sed, meanea, We, att, cb, hbn);

    k_bnstats<<<1024, 256, 0, stream>>>(hbn, bnsum, bnsq);
    k_bnapply<<<16000, 256, 0, stream>>>(hbn, bnsum, bnsq, gam, bet, wroot, wrel, r_, rel_);
    k_score<<<16000, 256, 0, stream>>>(r_, rel_, offs, sed, gcb, score);
    k_topk<<<32, 1024, 0, stream>>>(score, hbn, xb);

    k_mlp<<<BB, 128, 0, stream>>>(xb, W1, b1, W2, b2, Wo, bo, (float*)d_out);
}

// Round 5
// 1153.223 us; speedup vs baseline: 1.0872x; 1.0872x over previous
//
#include <hip/hip_runtime.h>
#include <hip/hip_bf16.h>
#include <math.h>

#define NN 32000        // total nodes
#define EE 640000       // edges
#define CC 128          // hidden
#define HC 384          // H*C
#define FIN 1038
#define KP 1056         // FIN padded to multiple of 32
#define KT 33           // KP/32
#define BB 16           // graphs
#define NPG 2000
#define KK 400

// per-branch strides
#define XLR_H  12288000u   // halves per branch for xl / xr (32000*384)
#define HBN_STR 4096000u
#define OFF_STR 32064u

// ---------------- workspace layout (float elements), 212 MB ----------------
#define XH_OFF     0u            // 16,896,000 fl = one branch x in fp16 [32000][1056]
#define XL_OFF     16896000u     // 12,288,000 fl = both branches xl fp16
#define XR_OFF     29184000u     // 12,288,000 fl = both branches xr fp16
#define HBN_OFF    41472000u     // 8,192,000 fl  = h fp32, both branches
#define SED_OFF    49664000u     // 2,560,000 fl  = packed edges int2, both branches
#define CNT_OFF    52224000u     // zero block: cnt(2*32000)+bnsum(2*128)+bnsq(2*128)+meanea(4)
#define BNSUM_OFF  52288000u
#define BNSQ_OFF   52288256u
#define MEANEA_OFF 52288512u
#define ZERO_BYTES ((52288516u - 52224000u) * 4u)
#define OFFS_OFF   52288576u     // 2 * 32064
#define CUR_OFF    52352704u     // 2 * 32000
#define R_OFF      52416704u     // 2 * 32000
#define REL_OFF    52480704u     // 2 * 32000
#define SCORE_OFF  52544704u     // 2 * 32000
#define XB_OFF     52608704u     // 4096
#define WTH_OFF    52612800u     // 405504 (f16 weights [768][1056]) -> end 53,018,304 fl

typedef __attribute__((ext_vector_type(8))) _Float16 f16x8;
typedef __attribute__((ext_vector_type(2))) _Float16 f16x2;
typedef __attribute__((ext_vector_type(4))) float f32x4;
typedef __attribute__((ext_vector_type(8))) unsigned short us8;

typedef const __attribute__((address_space(1))) unsigned int* gp1_t;
typedef __attribute__((address_space(3))) unsigned int* lp3_t;
__device__ __forceinline__ void gl_lds16(const void* g, void* l) {
    __builtin_amdgcn_global_load_lds((gp1_t)g, (lp3_t)l, 16, 0, 0);
}

// ---------------- fused: dst histogram + edge-attr mean (both branches) ----------------
__global__ __launch_bounds__(256) void k_prep(const int* __restrict__ ei0, const int* __restrict__ ei1,
                                              const float* __restrict__ ea0, const float* __restrict__ ea1,
                                              int* __restrict__ cnt, float* __restrict__ meanea) {
    int b = blockIdx.x;
    int br = (b >= 2500);
    int tid = threadIdx.x;
    int e = (b - br * 2500) * 256 + tid;
    const int* ei = br ? ei1 : ei0;
    const float* ea = br ? ea1 : ea0;
    cnt += br * NN; meanea += br * 2;
    float s0 = 0.f, s1 = 0.f;
    if (e < EE) {
        atomicAdd(&cnt[ei[EE + e]], 1);
        float2 t = ((const float2*)ea)[e];
        s0 = t.x; s1 = t.y;
    }
    __shared__ float r0[256], r1[256];
    r0[tid] = s0; r1[tid] = s1; __syncthreads();
    for (int st = 128; st; st >>= 1) {
        if (tid < st) { r0[tid] += r0[tid + st]; r1[tid] += r1[tid + st]; }
        __syncthreads();
    }
    if (tid == 0) { atomicAdd(&meanea[0], r0[0]); atomicAdd(&meanea[1], r1[0]); }
}

// ---------------- exclusive scan over 32000 counters (1 block per branch) ----------------
__global__ __launch_bounds__(1024) void k_scan(const int* __restrict__ cnt, int* __restrict__ offs, int* __restrict__ cur) {
    int br = blockIdx.x;
    cnt += br * NN; offs += br * OFF_STR; cur += br * NN;
    __shared__ int sb[1024];
    int tid = threadIdx.x;
    int base = tid * 32;
    int s = 0;
    for (int i = 0; i < 32; i++) { int idx = base + i; s += (idx < NN) ? cnt[idx] : 0; }
    sb[tid] = s; __syncthreads();
    for (int off = 1; off < 1024; off <<= 1) {
        int v = (tid >= off) ? sb[tid - off] : 0;
        __syncthreads();
        sb[tid] += v;
        __syncthreads();
    }
    int run = sb[tid] - s;  // exclusive prefix
    for (int i = 0; i < 32; i++) {
        int idx = base + i;
        if (idx < NN) { int c = cnt[idx]; offs[idx] = run; cur[idx] = run; run += c; }
    }
    if (tid == 1023) offs[NN] = run;
}

// ---------------- scatter edges sorted by dst, packed {src, half2 ea} 8B (both branches) ----------------
__global__ __launch_bounds__(256) void k_scatter(const int* __restrict__ ei0, const int* __restrict__ ei1,
                                                 const float* __restrict__ ea0, const float* __restrict__ ea1,
                                                 int* __restrict__ cur, int2* __restrict__ sed) {
    int b = blockIdx.x;
    int br = (b >= 2500);
    int e = (b - br * 2500) * 256 + threadIdx.x;
    const int* ei = br ? ei1 : ei0;
    const float* ea = br ? ea1 : ea0;
    cur += br * NN; sed += br * EE;
    if (e < EE) {
        int d = ei[EE + e];
        int p = atomicAdd(&cur[d], 1);
        float2 t = ((const float2*)ea)[e];
        f16x2 h; h[0] = (_Float16)t.x; h[1] = (_Float16)t.y;
        int2 pk;
        pk.x = ei[e];
        pk.y = __builtin_bit_cast(int, h);
        sed[p] = pk;
    }
}

// ---------------- weights: transpose to N-major [768][1056], fp16 ----------------
__global__ __launch_bounds__(256) void k_cvtW(const float* __restrict__ Wl_, const float* __restrict__ Wr_,
                                              unsigned short* __restrict__ Bh) {
    int idx = blockIdx.x * 256 + threadIdx.x;
    if (idx >= 768 * (KP / 8)) return;
    int n = idx / (KP / 8);
    int seg = idx - n * (KP / 8);
    int c0 = seg * 8;
    const float* W = (n < HC) ? Wl_ : Wr_;
    int nc = (n < HC) ? n : n - HC;
    us8 h8;
#pragma unroll
    for (int j = 0; j < 8; ++j) {
        int k = c0 + j;
        float v = (k < FIN) ? W[(size_t)k * HC + nc] : 0.f;
        _Float16 h = (_Float16)v;   // RTN
        h8[j] = __builtin_bit_cast(unsigned short, h);
    }
    *(us8*)&Bh[(size_t)n * KP + c0] = h8;
}

// ---------------- x fp32 -> fp16 [32000][1056] (one branch), BW-bound ----------------
__global__ __launch_bounds__(256) void k_cvtX(const float* __restrict__ x, _Float16* __restrict__ xh) {
    int idx = blockIdx.x * 256 + threadIdx.x;     // 32000 * 132 chunks of 8
    if (idx >= NN * (KP / 8)) return;
    int row = idx / (KP / 8);
    int c8 = idx - row * (KP / 8);
    int col = c8 * 8;
    const float* gp = x + (size_t)row * FIN + col;
    f16x8 o;
    if (col + 8 <= FIN) {
        float2 v01 = ((const float2*)gp)[0];
        float2 v23 = ((const float2*)gp)[1];
        float2 v45 = ((const float2*)gp)[2];
        float2 v67 = ((const float2*)gp)[3];
        o[0] = (_Float16)v01.x; o[1] = (_Float16)v01.y;
        o[2] = (_Float16)v23.x; o[3] = (_Float16)v23.y;
        o[4] = (_Float16)v45.x; o[5] = (_Float16)v45.y;
        o[6] = (_Float16)v67.x; o[7] = (_Float16)v67.y;
    } else {
#pragma unroll
        for (int j = 0; j < 8; ++j) o[j] = (_Float16)((col + j < FIN) ? gp[j] : 0.f);
    }
    *(f16x8*)&xh[(size_t)row * KP + col] = o;
}

// ---------------- MFMA GEMM, fp16, pure-DMA staging (m97 structure), one branch ----------------
// C[32000,768] = xh[32000,1056] @ Bh^T. A and B both staged via global_load_lds (16B),
// 2-barrier loop, zero in-loop VALU staging work. Outputs fp16 xl (with bias) / xr.
__global__ __launch_bounds__(256) void k_gemm3(const _Float16* __restrict__ xh,
                                               const unsigned short* __restrict__ Bh,
                                               const float* __restrict__ bias, int br,
                                               float* __restrict__ ws) {
    __shared__ _Float16 sA[128 * 32], sB[128 * 32];
    const int b2 = blockIdx.x;
    const int xcd = b2 & 7, slot = b2 >> 3;
    const int t = xcd * 188 + slot;          // 1504/8 = 188 slots per XCD
    if (t >= 1500) return;
    const int mt = t / 6, nt = t - mt * 6;
    const int bm = mt * 128, bn = nt * 128;

    _Float16* xlh = (_Float16*)(ws + XL_OFF) + (size_t)br * XLR_H;
    _Float16* xrh = (_Float16*)(ws + XR_OFF) + (size_t)br * XLR_H;

    const int tid = threadIdx.x;
    const int wave = tid >> 6, lane = tid & 63;
    const int wm = (wave >> 1) * 64, wn = (wave & 1) * 64;
    const int quad = lane >> 4, l15 = lane & 15;

    // staging addressing (identical for A and B): rows wave*16+(lane>>2) (+64), col (lane&3)*8
    const int srow = wave * 16 + (lane >> 2);
    const int scol = (lane & 3) * 8;
    const size_t gA0 = (size_t)(bm + srow) * KP + scol;
    const size_t gA1 = (size_t)(bm + 64 + srow) * KP + scol;
    const size_t gB0 = (size_t)(bn + srow) * KP + scol;
    const size_t gB1 = (size_t)(bn + 64 + srow) * KP + scol;
    const int lds0 = (wave * 16) * 32 + lane * 8;          // halves
    const int lds1 = (64 + wave * 16) * 32 + lane * 8;

    f32x4 acc[4][4];
#pragma unroll
    for (int i = 0; i < 4; ++i)
#pragma unroll
        for (int j = 0; j < 4; ++j) {
            f32x4 z = {0.f, 0.f, 0.f, 0.f};
            acc[i][j] = z;
        }

    const int aoff0 = (wm + l15) * 32 + quad * 8;   // + i*512 (f16 elements)
    const int boff0 = (wn + l15) * 32 + quad * 8;   // + j*512

    for (int kt = 0; kt < KT; ++kt) {
        const int kc = kt * 32;
        gl_lds16(xh + gA0 + kc, &sA[lds0]);
        gl_lds16(xh + gA1 + kc, &sA[lds1]);
        gl_lds16(Bh + gB0 + kc, &sB[lds0]);
        gl_lds16(Bh + gB1 + kc, &sB[lds1]);
        __syncthreads();   // drains vmcnt (4 DMA lines)
        f16x8 bfr[4];
#pragma unroll
        for (int j = 0; j < 4; ++j) bfr[j] = *(const f16x8*)&sB[boff0 + j * 512];
#pragma unroll
        for (int i = 0; i < 4; ++i) {
            f16x8 a = *(const f16x8*)&sA[aoff0 + i * 512];
#pragma unroll
            for (int j = 0; j < 4; ++j)
                acc[i][j] = __builtin_amdgcn_mfma_f32_16x16x32_f16(a, bfr[j], acc[i][j], 0, 0, 0);
        }
        __syncthreads();   // protect LDS before next stage
    }

    // epilogue: C/D layout col=lane&15, row=quad*4+reg. Block is purely xl or purely xr.
    const bool isL = (nt < 3);
    if (isL) {
#pragma unroll
        for (int j = 0; j < 4; ++j) {
            const int ncol = wn + j * 16 + l15;
            const float bj = bias[bn + ncol];
#pragma unroll
            for (int i = 0; i < 4; ++i) {
#pragma unroll
                for (int r = 0; r < 4; ++r) {
                    int m = bm + wm + i * 16 + quad * 4 + r;
                    xlh[(size_t)m * HC + bn + ncol] = (_Float16)(acc[i][j][r] + bj);
                }
            }
        }
    } else {
        const int nbase = bn - HC;
#pragma unroll
        for (int j = 0; j < 4; ++j) {
            const int ncol = wn + j * 16 + l15;
#pragma unroll
            for (int i = 0; i < 4; ++i) {
#pragma unroll
                for (int r = 0; r < 4; ++r) {
                    int m = bm + wm + i * 16 + quad * 4 + r;
                    xrh[(size_t)m * HC + nbase + ncol] = (_Float16)acc[i][j][r];
                }
            }
        }
    }
}

// ---------------- fused GATv2 aggregation: one wave per node, 2 edges/iter (32-lane halves) ----------------
__global__ __launch_bounds__(256) void k_gat(const unsigned short* __restrict__ xlhb, const unsigned short* __restrict__ xrhb,
                                             const int* __restrict__ offsb, const int2* __restrict__ sedb,
                                             const float* __restrict__ meaneab,
                                             const float* __restrict__ We, const float* __restrict__ att,
                                             const float* __restrict__ conv_bias, float* __restrict__ houtb) {
    int gwave = (blockIdx.x * 256 + threadIdx.x) >> 6;
    int lane = threadIdx.x & 63;
    int half = lane >> 5, l32 = lane & 31;
    int br = (gwave >= NN);
    int node = gwave - br * NN;
    const _Float16* xlh = (const _Float16*)xlhb + (size_t)br * XLR_H;
    const _Float16* xrh = (const _Float16*)xrhb + (size_t)br * XLR_H;
    const int* offs = offsb + br * OFF_STR;
    const int2* sed = sedb + br * EE;
    const float* meanea = meaneab + br * 2;
    float* hout = houtb + br * HBN_STR;

    // per-lane constants: pair q = l32 + 32*jj holds channels (2q, 2q+1); head = jj>>1
    f16x2 we0p[6], we1p[6], attp[6], xrp[6];
    const f16x2* xrw = (const f16x2*)(xrh + (size_t)node * HC);
#pragma unroll
    for (int jj = 0; jj < 6; ++jj) {
        int q = l32 + 32 * jj;
        float2 w0 = ((const float2*)We)[q];
        float2 w1 = ((const float2*)(We + HC))[q];
        float2 av = ((const float2*)att)[q];
        we0p[jj][0] = (_Float16)w0.x; we0p[jj][1] = (_Float16)w0.y;
        we1p[jj][0] = (_Float16)w1.x; we1p[jj][1] = (_Float16)w1.y;
        attp[jj][0] = (_Float16)av.x; attp[jj][1] = (_Float16)av.y;
        xrp[jj] = xrw[q];
    }
    _Float16 meh0 = (_Float16)(meanea[0] * (1.0f / EE));
    _Float16 meh1 = (_Float16)(meanea[1] * (1.0f / EE));

    int p0 = offs[node], p1 = offs[node + 1];
    int cntE = p1 - p0;
    int iters = (cntE + 2) >> 1;   // virtual list: t=0 self-loop, t=1..cntE real edges

    float den0 = 0.f, den1 = 0.f, den2 = 0.f;
    float accv[12];
#pragma unroll
    for (int k = 0; k < 12; ++k) accv[k] = 0.f;

    const f16x2 zero2 = {(_Float16)0.f, (_Float16)0.f};
    const f16x2 c02 = {(_Float16)0.2f, (_Float16)0.2f};

    for (int i = 0; i < iters; ++i) {
        int t = 2 * i + half;
        bool self = (t == 0);
        bool valid = (t <= cntE);
        int p = p0 + t - 1;
        if (p < p0) p = p0;
        if (p > EE - 1) p = EE - 1;
        int2 pk = sed[p];
        f16x2 eh = __builtin_bit_cast(f16x2, pk.y);
        int s = self ? node : pk.x;
        _Float16 e0 = self ? meh0 : eh[0];
        _Float16 e1 = self ? meh1 : eh[1];
        f16x2 e0p, e1p;
        e0p[0] = e0; e0p[1] = e0;
        e1p[0] = e1; e1p[1] = e1;

        const f16x2* xrow = (const f16x2*)(xlh + (size_t)s * HC);
        f16x2 xv[6];
#pragma unroll
        for (int jj = 0; jj < 6; ++jj) xv[jj] = xrow[l32 + 32 * jj];

        float pr0 = 0.f, pr1 = 0.f, pr2 = 0.f;
#pragma unroll
        for (int jj = 0; jj < 6; ++jj) {
            f16x2 u = xrp[jj] + e0p * we0p[jj];
            u = u + e1p * we1p[jj];
            f16x2 m = xv[jj] + u;
            f16x2 mx = __builtin_elementwise_max(m, zero2);
            f16x2 mn = __builtin_elementwise_min(m, zero2);
            f16x2 lk = mx + mn * c02;
#if __has_builtin(__builtin_amdgcn_fdot2)
            if (jj < 2)      pr0 = __builtin_amdgcn_fdot2(lk, attp[jj], pr0, false);
            else if (jj < 4) pr1 = __builtin_amdgcn_fdot2(lk, attp[jj], pr1, false);
            else             pr2 = __builtin_amdgcn_fdot2(lk, attp[jj], pr2, false);
#else
            float c = (float)lk[0] * (float)attp[jj][0] + (float)lk[1] * (float)attp[jj][1];
            if (jj < 2) pr0 += c; else if (jj < 4) pr1 += c; else pr2 += c;
#endif
        }
        // butterfly within the 32-lane half
#pragma unroll
        for (int msk = 16; msk; msk >>= 1) {
            pr0 += __shfl_xor(pr0, msk);
            pr1 += __shfl_xor(pr1, msk);
            pr2 += __shfl_xor(pr2, msk);
        }
        float w0 = valid ? __expf(pr0) : 0.f;
        float w1 = valid ? __expf(pr1) : 0.f;
        float w2 = valid ? __expf(pr2) : 0.f;
        den0 += w0; den1 += w1; den2 += w2;
#pragma unroll
        for (int jj = 0; jj < 6; ++jj) {
            float wh = (jj < 2) ? w0 : ((jj < 4) ? w1 : w2);
            accv[2 * jj]     += wh * (float)xv[jj][0];
            accv[2 * jj + 1] += wh * (float)xv[jj][1];
        }
    }

    // merge halves
#pragma unroll
    for (int k = 0; k < 12; ++k) accv[k] += __shfl_xor(accv[k], 32);
    den0 += __shfl_xor(den0, 32);
    den1 += __shfl_xor(den1, 32);
    den2 += __shfl_xor(den2, 32);

    if (half == 0) {
        float i0 = 1.f / den0, i1 = 1.f / den1, i2 = 1.f / den2;
#pragma unroll
        for (int jja = 0; jja < 2; ++jja) {
#pragma unroll
            for (int b = 0; b < 2; ++b) {
                int c = (((jja * 32 + l32) << 1) | b);
                float o = (accv[2 * jja + b] * i0 + accv[2 * (jja + 2) + b] * i1 +
                           accv[2 * (jja + 4) + b] * i2) * (1.f / 3.f) + conv_bias[c];
                o = (o > 0.f) ? o : 0.1f * o;
                hout[(size_t)node * CC + c] = o;
            }
        }
    }
}

// ---------------- batchnorm stats (both branches) ----------------
__global__ __launch_bounds__(256) void k_bnstats(const float* __restrict__ hb, float* __restrict__ bnsumb, float* __restrict__ bnsqb) {
    int b = blockIdx.x;
    int br = b >> 9, lb = b & 511;
    const float* h = hb + br * HBN_STR;
    float* bnsum = bnsumb + br * CC;
    float* bnsq = bnsqb + br * CC;
    int c = threadIdx.x & 127;
    int row0 = lb * 2 + (threadIdx.x >> 7);
    float s = 0.f, ss = 0.f;
    for (int n = row0; n < NN; n += 1024) {
        float v = h[(size_t)n * CC + c];
        s += v; ss += v * v;
    }
    atomicAdd(&bnsum[c], s);
    atomicAdd(&bnsq[c], ss);
}

// ---------------- BN apply (folds bnfinal) + scorer dot products (both branches) ----------------
__global__ __launch_bounds__(256) void k_bnapply(float* __restrict__ hb, const float* __restrict__ bnsumb,
                                                 const float* __restrict__ bnsqb,
                                                 const float* __restrict__ gamma, const float* __restrict__ beta,
                                                 const float* __restrict__ wroot,
                                                 const float* __restrict__ wrel, float* __restrict__ r_b, float* __restrict__ rel_b) {
    int gwave = (blockIdx.x * 256 + threadIdx.x) >> 6;
    int lane = threadIdx.x & 63;
    int br = (gwave >= NN);
    int wave = gwave - br * NN;
    float* h = hb + br * HBN_STR;
    const float* bnsum = bnsumb + br * CC;
    const float* bnsq = bnsqb + br * CC;
    float* r_ = r_b + br * NN;
    float* rel_ = rel_b + br * NN;

    float mu0 = bnsum[lane] * (1.f / NN);
    float var0 = bnsq[lane] * (1.f / NN) - mu0 * mu0;
    float sc0 = gamma[lane] * rsqrtf(var0 + 1e-5f);
    float sh0 = beta[lane] - mu0 * sc0;
    float mu1 = bnsum[64 + lane] * (1.f / NN);
    float var1 = bnsq[64 + lane] * (1.f / NN) - mu1 * mu1;
    float sc1 = gamma[64 + lane] * rsqrtf(var1 + 1e-5f);
    float sh1 = beta[64 + lane] - mu1 * sc1;

    size_t base = (size_t)wave * CC;
    float v0 = h[base + lane], v1 = h[base + 64 + lane];
    v0 = v0 * sc0 + sh0;
    v1 = v1 * sc1 + sh1;
    h[base + lane] = v0;
    h[base + 64 + lane] = v1;
    float pr = v0 * wroot[lane] + v1 * wroot[64 + lane];
    float pl = v0 * wrel[lane] + v1 * wrel[64 + lane];
#pragma unroll
    for (int m = 32; m; m >>= 1) {
        pr += __shfl_xor(pr, m);
        pl += __shfl_xor(pl, m);
    }
    if (lane == 0) { r_[wave] = pr; rel_[wave] = pl; }
}

// ---------------- scorer aggregation + tanh (both branches) ----------------
__global__ __launch_bounds__(256) void k_score(const float* __restrict__ r_b, const float* __restrict__ rel_b,
                                               const int* __restrict__ offsb, const int2* __restrict__ sedb,
                                               const float* __restrict__ gcb, float* __restrict__ scoreb) {
    int gwave = (blockIdx.x * 256 + threadIdx.x) >> 6;
    int lane = threadIdx.x & 63;
    int br = (gwave >= NN);
    int wave = gwave - br * NN;
    const float* r_ = r_b + br * NN;
    const float* rel_ = rel_b + br * NN;
    const int* offs = offsb + br * OFF_STR;
    const int2* sed = sedb + br * EE;
    float* score = scoreb + br * NN;
    int p0 = offs[wave], p1 = offs[wave + 1];
    float s = 0.f;
    for (int p = p0 + lane; p < p1; p += 64) s += rel_[sed[p].x];
#pragma unroll
    for (int m = 32; m; m >>= 1) s += __shfl_xor(s, m);
    if (lane == 0) score[wave] = tanhf(r_[wave] + s + gcb[0]);
}

// ---------------- per-graph top-K (exact bitonic sort of 2048) + weighted mean pool ----------------
__global__ __launch_bounds__(1024) void k_topk(const float* __restrict__ scoreb, const float* __restrict__ hb,
                                               float* __restrict__ xbout) {
    __shared__ float sv[2048];
    __shared__ int si[2048];
    __shared__ float red[8][128];
    int b = blockIdx.x, tid = threadIdx.x;
    int br = b >> 4, g = b & 15;
    const float* score = scoreb + br * NN;
    const float* h = hb + br * HBN_STR;
    for (int i = tid; i < 2048; i += 1024) {
        sv[i] = (i < NPG) ? score[g * NPG + i] : -2.0f;  // scores in [-1,1]
        si[i] = i;
    }
    __syncthreads();
    for (int k = 2; k <= 2048; k <<= 1) {
        for (int j = k >> 1; j > 0; j >>= 1) {
            for (int t = tid; t < 2048; t += 1024) {
                int ixj = t ^ j;
                if (ixj > t) {
                    bool up = ((t & k) == 0);  // descending overall
                    float a = sv[t], bv = sv[ixj];
                    bool sw = up ? (a < bv) : (a > bv);
                    if (sw) {
                        sv[t] = bv; sv[ixj] = a;
                        int tmp = si[t]; si[t] = si[ixj]; si[ixj] = tmp;
                    }
                }
            }
            __syncthreads();
        }
    }
    int grp = tid >> 7, c = tid & 127;
    float a = 0.f;
    for (int kk = grp; kk < KK; kk += 8) {
        int node = g * NPG + si[kk];
        a += sv[kk] * h[(size_t)node * CC + c];
    }
    red[grp][c] = a;
    __syncthreads();
    if (tid < 128) {
        float v = (red[0][tid] + red[1][tid] + red[2][tid] + red[3][tid] +
                   red[4][tid] + red[5][tid] + red[6][tid] + red[7][tid]) * (1.f / KK);
        xbout[(br * BB + g) * CC + tid] = v;
    }
}

// ---------------- final MLP ----------------
__global__ __launch_bounds__(128) void k_mlp(const float* __restrict__ xb, const float* __restrict__ W1,
                                             const float* __restrict__ b1, const float* __restrict__ W2,
                                             const float* __restrict__ b2, const float* __restrict__ Wo,
                                             const float* __restrict__ bo, float* __restrict__ out) {
    int g = blockIdx.x, tid = threadIdx.x;
    __shared__ float xc[256], l1[128], l2[64];
    xc[tid] = xb[g * CC + tid];
    xc[128 + tid] = xb[BB * CC + g * CC + tid];
    __syncthreads();
    float s = b1[tid];
    for (int i = 0; i < 256; i++) s += xc[i] * W1[i * 128 + tid];
    l1[tid] = (s > 0.f) ? s : 0.1f * s;
    __syncthreads();
    if (tid < 64) {
        float s2 = b2[tid];
        for (int i = 0; i < 128; i++) s2 += l1[i] * W2[i * 64 + tid];
        l2[tid] = (s2 > 0.f) ? s2 : 0.1f * s2;
    }
    __syncthreads();
    if (tid < 64) {
        float p = l2[tid] * Wo[tid];
#pragma unroll
        for (int m = 32; m; m >>= 1) p += __shfl_xor(p, m);
        if (tid == 0) out[g] = 1.f / (1.f + __expf(-(p + bo[0])));
    }
}

extern "C" void kernel_launch(void* const* d_in, const int* in_sizes, int n_in,
                              void* d_out, int out_size, void* d_ws, size_t ws_size,
                              hipStream_t stream) {
    (void)in_sizes; (void)n_in; (void)out_size; (void)ws_size;
    const float* x0   = (const float*)d_in[0];
    const float* x1   = (const float*)d_in[1];
    const int*   ei0  = (const int*)d_in[2];
    const int*   ei1  = (const int*)d_in[3];
    const float* ea0  = (const float*)d_in[4];
    const float* ea1  = (const float*)d_in[5];
    const float* Wl   = (const float*)d_in[6];
    const float* bl   = (const float*)d_in[7];
    const float* Wr   = (const float*)d_in[8];
    const float* We   = (const float*)d_in[9];
    const float* att  = (const float*)d_in[10];
    const float* cb   = (const float*)d_in[11];
    const float* gam  = (const float*)d_in[12];
    const float* bet  = (const float*)d_in[13];
    const float* wrel = (const float*)d_in[14];
    const float* wroot= (const float*)d_in[15];
    const float* gcb  = (const float*)d_in[16];
    const float* W1   = (const float*)d_in[17];
    const float* b1   = (const float*)d_in[18];
    const float* W2   = (const float*)d_in[19];
    const float* b2   = (const float*)d_in[20];
    const float* Wo   = (const float*)d_in[21];
    const float* bo   = (const float*)d_in[22];

    float* ws = (float*)d_ws;
    _Float16* xh  = (_Float16*)(ws + XH_OFF);
    unsigned short* xlh = (unsigned short*)(ws + XL_OFF);
    unsigned short* xrh = (unsigned short*)(ws + XR_OFF);
    float*  hbn   = ws + HBN_OFF;
    int2*   sed   = (int2*)(ws + SED_OFF);
    int*    cnt   = (int*)(ws + CNT_OFF);
    float*  bnsum = ws + BNSUM_OFF;
    float*  bnsq  = ws + BNSQ_OFF;
    float*  meanea= ws + MEANEA_OFF;
    int*    offs  = (int*)(ws + OFFS_OFF);
    int*    cur   = (int*)(ws + CUR_OFF);
    float*  r_    = ws + R_OFF;
    float*  rel_  = ws + REL_OFF;
    float*  score = ws + SCORE_OFF;
    float*  xb    = ws + XB_OFF;
    unsigned short* Wth = (unsigned short*)(ws + WTH_OFF);

    hipMemsetAsync(cnt, 0, ZERO_BYTES, stream);  // cnt + bnsum + bnsq + meanea, both branches
    k_cvtW<<<(768 * (KP / 8) + 255) / 256, 256, 0, stream>>>(Wl, Wr, Wth);

    k_prep<<<5000, 256, 0, stream>>>(ei0, ei1, ea0, ea1, cnt, meanea);
    k_scan<<<2, 1024, 0, stream>>>(cnt, offs, cur);
    k_scatter<<<5000, 256, 0, stream>>>(ei0, ei1, ea0, ea1, cur, sed);

    k_cvtX<<<(NN * (KP / 8) + 255) / 256, 256, 0, stream>>>(x0, xh);
    k_gemm3<<<1504, 256, 0, stream>>>(xh, Wth, bl, 0, ws);
    k_cvtX<<<(NN * (KP / 8) + 255) / 256, 256, 0, stream>>>(x1, xh);
    k_gemm3<<<1504, 256, 0, stream>>>(xh, Wth, bl, 1, ws);

    k_gat<<<16000, 256, 0, stream>>>(xlh, xrh, offs, sed, meanea, We, att, cb, hbn);

    k_bnstats<<<1024, 256, 0, stream>>>(hbn, bnsum, bnsq);
    k_bnapply<<<16000, 256, 0, stream>>>(hbn, bnsum, bnsq, gam, bet, wroot, wrel, r_, rel_);
    k_score<<<16000, 256, 0, stream>>>(r_, rel_, offs, sed, gcb, score);
    k_topk<<<32, 1024, 0, stream>>>(score, hbn, xb);

    k_mlp<<<BB, 128, 0, stream>>>(xb, W1, b1, W2, b2, Wo, bo, (float*)d_out);
}